// Round 7
// baseline (1030.972 us; speedup 1.0000x reference)
//
#include <hip/hip_runtime.h>

#define Cc 256
#define Hh 96
#define Ww 128
#define CH_STRIDE (Hh * Ww)   // 12288 floats per channel plane

// 36 FMAs on one channel: acc[dj].{x,y,z,w} += a.{x,y,z,w} * win[dj + {0,1,2,3}]
#define FMA36(a, f0, f1, f2)                                        \
  do {                                                              \
    const float wn[12] = {f0.x, f0.y, f0.z, f0.w,                   \
                          f1.x, f1.y, f1.z, f1.w,                   \
                          f2.x, f2.y, f2.z, f2.w};                  \
    _Pragma("unroll")                                               \
    for (int dj = 0; dj < 9; ++dj) {                                \
      acc[dj].x += a.x * wn[dj + 0];                                \
      acc[dj].y += a.y * wn[dj + 1];                                \
      acc[dj].z += a.z * wn[dj + 2];                                \
      acc[dj].w += a.w * wn[dj + 3];                                \
    }                                                               \
  } while (0)

// load channel `ch` window into register set S (a, f0, f1, f2)
#define LOADSET(sa, sf0, sf1, sf2, ch)                              \
  do {                                                              \
    const float* q1 = p1base + (size_t)(ch) * CH_STRIDE;            \
    const float* q2 = p2base + (size_t)(ch) * CH_STRIDE;            \
    sa  = *(const float4*)(q1);                                     \
    sf1 = *(const float4*)(q2);                                     \
    sf0 = make_float4(0.f, 0.f, 0.f, 0.f);                          \
    sf2 = make_float4(0.f, 0.f, 0.f, 0.f);                          \
    if (ok_f0) sf0 = *(const float4*)(q2 - 4);                      \
    if (ok_f2) sf2 = *(const float4*)(q2 + 4);                      \
  } while (0)

__global__ __launch_bounds__(256, 4)
void corr_kernel(const float* __restrict__ x1, const float* __restrict__ x2,
                 float* __restrict__ out) {
  const int tid  = threadIdx.x;
  // XCD-chunked swizzle: grid 864 = 8 XCDs * 108 contiguous blocks (bijective)
  const int bid  = blockIdx.x;
  const int sbid = (bid & 7) * 108 + (bid >> 3);

  const int wid   = (sbid * 256 + tid) >> 6;  // 0..3455, wave-uniform
  const int lane  = tid & 63;
  const int tw    = lane & 31;   // 32 w-threads, 4 px each
  const int ty    = lane >> 5;   // row within strip
  const int g     = wid % 9;     // di
  const int strip = wid / 9;     // 0..383
  const int hs    = strip % 48;
  const int b     = strip / 48;
  const int h     = hs * 2 + ty;
  const int w4    = tw * 4;

  // x2 row for this di; clamp address, zero result via scale if OOB
  const int  hx2    = h + g - 4;
  const bool row_ok = (hx2 >= 0) && (hx2 < Hh);
  const int  hc     = row_ok ? hx2 : 0;
  // column-pad masks: f0 covers cols [w4-4,w4), f2 covers [w4+4,w4+8)
  const bool ok_f0 = (tw != 0);
  const bool ok_f2 = (tw != 31);

  const float* p1base = x1 + (((size_t)(b * Cc) * Hh + h)  * Ww + w4);
  const float* p2base = x2 + (((size_t)(b * Cc) * Hh + hc) * Ww + w4);

  float4 acc[9];
#pragma unroll
  for (int j = 0; j < 9; ++j) acc[j] = make_float4(0.f, 0.f, 0.f, 0.f);

  // ---- 4-set rotating pipeline, prefetch distance 3 compute-blocks ----
  float4 s0a, s0f0, s0f1, s0f2;
  float4 s1a, s1f0, s1f1, s1f2;
  float4 s2a, s2f0, s2f1, s2f2;
  float4 s3a, s3f0, s3f1, s3f2;

  LOADSET(s0a, s0f0, s0f1, s0f2, 0);
  LOADSET(s1a, s1f0, s1f1, s1f2, 1);
  LOADSET(s2a, s2f0, s2f1, s2f2, 2);
  LOADSET(s3a, s3f0, s3f1, s3f2, 3);

  for (int c = 0; c < Cc; c += 4) {
    const int n0 = (c + 4 < Cc) ? c + 4 : Cc - 1;  // tail reload (unused result)
    const int n1 = (c + 5 < Cc) ? c + 5 : Cc - 1;
    const int n2 = (c + 6 < Cc) ? c + 6 : Cc - 1;
    const int n3 = (c + 7 < Cc) ? c + 7 : Cc - 1;
    FMA36(s0a, s0f0, s0f1, s0f2);
    LOADSET(s0a, s0f0, s0f1, s0f2, n0);
    FMA36(s1a, s1f0, s1f1, s1f2);
    LOADSET(s1a, s1f0, s1f1, s1f2, n1);
    FMA36(s2a, s2f0, s2f1, s2f2);
    LOADSET(s2a, s2f0, s2f1, s2f2, n2);
    FMA36(s3a, s3f0, s3f1, s3f2);
    LOADSET(s3a, s3f0, s3f1, s3f2, n3);
  }

  // ---- epilogue: scale (0 if row OOB -> whole di-plane is pad zeros) ----
  const float scale = row_ok ? (1.0f / (float)Cc) : 0.0f;
  float* po = out + (((size_t)(b * 81 + g * 9) * Hh + h) * Ww + w4);
#pragma unroll
  for (int dj = 0; dj < 9; ++dj) {
    float4 v = make_float4(acc[dj].x * scale, acc[dj].y * scale,
                           acc[dj].z * scale, acc[dj].w * scale);
    *(float4*)(po + (size_t)dj * CH_STRIDE) = v;
  }
}

extern "C" void kernel_launch(void* const* d_in, const int* in_sizes, int n_in,
                              void* d_out, int out_size, void* d_ws, size_t ws_size,
                              hipStream_t stream) {
  const float* x1 = (const float*)d_in[0];
  const float* x2 = (const float*)d_in[1];
  float* out = (float*)d_out;
  // 8 b * 48 strips * 9 di * 64 lanes = 221184 threads = 864 * 256
  corr_kernel<<<864, 256, 0, stream>>>(x1, x2, out);
}

// Round 9
// 134.116 us; speedup vs baseline: 7.6872x; 7.6872x over previous
//
#include <hip/hip_runtime.h>

#define Cc 256
#define Hh 96
#define Ww 128
#define CH_STRIDE (Hh * Ww)   // 12288 floats per channel plane

// 36 FMAs on one channel: acc[dj].{x,y,z,w} += a.{x,y,z,w} * win[dj + {0,1,2,3}]
#define FMA36(a, f0, f1, f2)                                        \
  do {                                                              \
    const float wn[12] = {f0.x, f0.y, f0.z, f0.w,                   \
                          f1.x, f1.y, f1.z, f1.w,                   \
                          f2.x, f2.y, f2.z, f2.w};                  \
    _Pragma("unroll")                                               \
    for (int dj = 0; dj < 9; ++dj) {                                \
      acc[dj].x += a.x * wn[dj + 0];                                \
      acc[dj].y += a.y * wn[dj + 1];                                \
      acc[dj].z += a.z * wn[dj + 2];                                \
      acc[dj].w += a.w * wn[dj + 3];                                \
    }                                                               \
  } while (0)

__global__ __launch_bounds__(256)
void corr_kernel(const float* __restrict__ x1, const float* __restrict__ x2,
                 float* __restrict__ out) {
  const int tid  = threadIdx.x;
  // XCD-chunked swizzle: grid 864 = 8 XCDs * 108 contiguous blocks (bijective).
  // Round-robin XCD assignment means blocks sbid, sbid+8 land on one XCD; we
  // want CONTIGUOUS sbid on one XCD so strips sharing x2 rows share an L2.
  const int bid  = blockIdx.x;
  const int sbid = (bid & 7) * 108 + (bid >> 3);

  const int wid   = (sbid * 256 + tid) >> 6;  // 0..3455, wave-uniform
  const int lane  = tid & 63;
  const int tw    = lane & 31;   // 32 w-threads, 4 px each
  const int ty    = lane >> 5;   // row within strip
  const int g     = wid % 9;     // di
  const int strip = wid / 9;     // 0..383
  const int hs    = strip % 48;
  const int b     = strip / 48;
  const int h     = hs * 2 + ty;
  const int w4    = tw * 4;

  // x2 row for this di; clamp address, zero result via scale if OOB
  const int  hx2    = h + g - 4;
  const bool row_ok = (hx2 >= 0) && (hx2 < Hh);
  const int  hc     = row_ok ? hx2 : 0;
  // column-pad masks: f0 covers cols [w4-4,w4), f2 covers [w4+4,w4+8)
  const bool ok_f0 = (tw != 0);    // w4==0  -> cols -4..-1  are pad zeros
  const bool ok_f2 = (tw != 31);   // w4==124-> cols 128..131 are pad zeros

  const float* p1base = x1 + (((size_t)(b * Cc) * Hh + h)  * Ww + w4);
  const float* p2base = x2 + (((size_t)(b * Cc) * Hh + hc) * Ww + w4);

  float4 acc[9];
#pragma unroll
  for (int j = 0; j < 9; ++j) acc[j] = make_float4(0.f, 0.f, 0.f, 0.f);

  // ---- 1-deep ping-pong pipeline over channels (known-good r6 structure) ----
  float4 aA  = *(const float4*)(p1base);
  float4 f1A = *(const float4*)(p2base);
  float4 f2A = *(const float4*)(p2base + 4);
  float4 f0A = make_float4(0.f, 0.f, 0.f, 0.f);
  if (ok_f0) f0A = *(const float4*)(p2base - 4);
  if (!ok_f2) f2A = make_float4(0.f, 0.f, 0.f, 0.f);

  for (int c = 0; c < Cc; c += 2) {
    // prefetch channel c+1 into set B
    {
      const float* q1 = p1base + (size_t)(c + 1) * CH_STRIDE;
      const float* q2 = p2base + (size_t)(c + 1) * CH_STRIDE;
      float4 aB  = *(const float4*)(q1);
      float4 f1B = *(const float4*)(q2);
      float4 f2B = make_float4(0.f, 0.f, 0.f, 0.f);
      float4 f0B = make_float4(0.f, 0.f, 0.f, 0.f);
      if (ok_f2) f2B = *(const float4*)(q2 + 4);
      if (ok_f0) f0B = *(const float4*)(q2 - 4);

      FMA36(aA, f0A, f1A, f2A);

      // prefetch channel c+2 into set A ((c+2)&255 wraps to 0 on last iter; unused)
      const int c2 = (c + 2) & (Cc - 1);
      const float* r1 = p1base + (size_t)c2 * CH_STRIDE;
      const float* r2 = p2base + (size_t)c2 * CH_STRIDE;
      aA  = *(const float4*)(r1);
      f1A = *(const float4*)(r2);
      f2A = make_float4(0.f, 0.f, 0.f, 0.f);
      f0A = make_float4(0.f, 0.f, 0.f, 0.f);
      if (ok_f2) f2A = *(const float4*)(r2 + 4);
      if (ok_f0) f0A = *(const float4*)(r2 - 4);

      FMA36(aB, f0B, f1B, f2B);
    }
  }

  // ---- epilogue: scale (0 if row OOB -> whole di-plane is pad zeros) ----
  const float scale = row_ok ? (1.0f / (float)Cc) : 0.0f;
  float* po = out + (((size_t)(b * 81 + g * 9) * Hh + h) * Ww + w4);
#pragma unroll
  for (int dj = 0; dj < 9; ++dj) {
    float4 v = make_float4(acc[dj].x * scale, acc[dj].y * scale,
                           acc[dj].z * scale, acc[dj].w * scale);
    *(float4*)(po + (size_t)dj * CH_STRIDE) = v;
  }
}

extern "C" void kernel_launch(void* const* d_in, const int* in_sizes, int n_in,
                              void* d_out, int out_size, void* d_ws, size_t ws_size,
                              hipStream_t stream) {
  const float* x1 = (const float*)d_in[0];
  const float* x2 = (const float*)d_in[1];
  float* out = (float*)d_out;
  // 8 b * 48 strips * 9 di * 64 lanes = 221184 threads = 864 * 256
  corr_kernel<<<864, 256, 0, stream>>>(x1, x2, out);
}

// Round 10
// 132.021 us; speedup vs baseline: 7.8091x; 1.0159x over previous
//
#include <hip/hip_runtime.h>

#define Cc 256
#define Hh 96
#define Ww 128
#define CH_STRIDE (Hh * Ww)   // 12288 floats per channel plane

// 36 FMAs on one channel: acc[dj].{x,y,z,w} += a.{x,y,z,w} * win[dj + {0,1,2,3}]
#define FMA36(a, f0, f1, f2)                                        \
  do {                                                              \
    const float wn[12] = {f0.x, f0.y, f0.z, f0.w,                   \
                          f1.x, f1.y, f1.z, f1.w,                   \
                          f2.x, f2.y, f2.z, f2.w};                  \
    _Pragma("unroll")                                               \
    for (int dj = 0; dj < 9; ++dj) {                                \
      acc[dj].x += a.x * wn[dj + 0];                                \
      acc[dj].y += a.y * wn[dj + 1];                                \
      acc[dj].z += a.z * wn[dj + 2];                                \
      acc[dj].w += a.w * wn[dj + 3];                                \
    }                                                               \
  } while (0)

// load channel `ch` window into register set S (a, f0, f1, f2)
#define LOADSET(sa, sf0, sf1, sf2, ch)                              \
  do {                                                              \
    const float* q1 = p1base + (size_t)(ch) * CH_STRIDE;            \
    const float* q2 = p2base + (size_t)(ch) * CH_STRIDE;            \
    sa  = *(const float4*)(q1);                                     \
    sf1 = *(const float4*)(q2);                                     \
    sf0 = make_float4(0.f, 0.f, 0.f, 0.f);                          \
    sf2 = make_float4(0.f, 0.f, 0.f, 0.f);                          \
    if (ok_f0) sf0 = *(const float4*)(q2 - 4);                      \
    if (ok_f2) sf2 = *(const float4*)(q2 + 4);                      \
  } while (0)

// NOTE: plain __launch_bounds__(256) — round 7's (256,4) clamped VGPR to 64
// and spilled the pipeline (WRITE_SIZE 2.3 GB). Occupancy is grid-limited
// (3.375 blocks/CU) so up to ~128 VGPR costs nothing.
__global__ __launch_bounds__(256)
void corr_kernel(const float* __restrict__ x1, const float* __restrict__ x2,
                 float* __restrict__ out) {
  const int tid  = threadIdx.x;
  // XCD-chunked swizzle (proven r9: FETCH 435->106 MB): 864 = 8 XCDs * 108.
  const int bid  = blockIdx.x;
  const int sbid = (bid & 7) * 108 + (bid >> 3);

  const int wid   = (sbid * 256 + tid) >> 6;  // 0..3455, wave-uniform
  const int lane  = tid & 63;
  const int tw    = lane & 31;   // 32 w-threads, 4 px each
  const int ty    = lane >> 5;   // row within strip
  const int g     = wid % 9;     // di
  const int strip = wid / 9;     // 0..383
  const int hs    = strip % 48;
  const int b     = strip / 48;
  const int h     = hs * 2 + ty;
  const int w4    = tw * 4;

  // x2 row for this di; clamp address, zero result via scale if OOB
  const int  hx2    = h + g - 4;
  const bool row_ok = (hx2 >= 0) && (hx2 < Hh);
  const int  hc     = row_ok ? hx2 : 0;
  // column-pad masks: f0 covers cols [w4-4,w4), f2 covers [w4+4,w4+8)
  const bool ok_f0 = (tw != 0);
  const bool ok_f2 = (tw != 31);

  const float* p1base = x1 + (((size_t)(b * Cc) * Hh + h)  * Ww + w4);
  const float* p2base = x2 + (((size_t)(b * Cc) * Hh + hc) * Ww + w4);

  float4 acc[9];
#pragma unroll
  for (int j = 0; j < 9; ++j) acc[j] = make_float4(0.f, 0.f, 0.f, 0.f);

  // ---- 4-set rotating pipeline, prefetch distance 3 compute-blocks ----
  float4 s0a, s0f0, s0f1, s0f2;
  float4 s1a, s1f0, s1f1, s1f2;
  float4 s2a, s2f0, s2f1, s2f2;
  float4 s3a, s3f0, s3f1, s3f2;

  LOADSET(s0a, s0f0, s0f1, s0f2, 0);
  LOADSET(s1a, s1f0, s1f1, s1f2, 1);
  LOADSET(s2a, s2f0, s2f1, s2f2, 2);
  LOADSET(s3a, s3f0, s3f1, s3f2, 3);

  for (int c = 0; c < Cc; c += 4) {
    const int n0 = (c + 4 < Cc) ? c + 4 : Cc - 1;  // tail reload (unused result)
    const int n1 = (c + 5 < Cc) ? c + 5 : Cc - 1;
    const int n2 = (c + 6 < Cc) ? c + 6 : Cc - 1;
    const int n3 = (c + 7 < Cc) ? c + 7 : Cc - 1;
    FMA36(s0a, s0f0, s0f1, s0f2);
    LOADSET(s0a, s0f0, s0f1, s0f2, n0);
    FMA36(s1a, s1f0, s1f1, s1f2);
    LOADSET(s1a, s1f0, s1f1, s1f2, n1);
    FMA36(s2a, s2f0, s2f1, s2f2);
    LOADSET(s2a, s2f0, s2f1, s2f2, n2);
    FMA36(s3a, s3f0, s3f1, s3f2);
    LOADSET(s3a, s3f0, s3f1, s3f2, n3);
  }

  // ---- epilogue: scale (0 if row OOB -> whole di-plane is pad zeros) ----
  const float scale = row_ok ? (1.0f / (float)Cc) : 0.0f;
  float* po = out + (((size_t)(b * 81 + g * 9) * Hh + h) * Ww + w4);
#pragma unroll
  for (int dj = 0; dj < 9; ++dj) {
    float4 v = make_float4(acc[dj].x * scale, acc[dj].y * scale,
                           acc[dj].z * scale, acc[dj].w * scale);
    *(float4*)(po + (size_t)dj * CH_STRIDE) = v;
  }
}

extern "C" void kernel_launch(void* const* d_in, const int* in_sizes, int n_in,
                              void* d_out, int out_size, void* d_ws, size_t ws_size,
                              hipStream_t stream) {
  const float* x1 = (const float*)d_in[0];
  const float* x2 = (const float*)d_in[1];
  float* out = (float*)d_out;
  // 8 b * 48 strips * 9 di * 64 lanes = 221184 threads = 864 * 256
  corr_kernel<<<864, 256, 0, stream>>>(x1, x2, out);
}

// Round 12
// 123.904 us; speedup vs baseline: 8.3207x; 1.0655x over previous
//
#include <hip/hip_runtime.h>

#define Cc 256
#define Hh 96
#define Ww 128
#define CH_STRIDE (Hh * Ww)   // 12288 floats per channel plane

typedef __attribute__((ext_vector_type(8))) short bf16x8;  // 8 bf16 in 4 VGPRs
typedef __attribute__((ext_vector_type(4))) float f32x4;

static __device__ __forceinline__ unsigned cvt_pk(float lo, float hi) {
  unsigned r;
  asm("v_cvt_pk_bf16_f32 %0, %1, %2" : "=v"(r) : "v"(lo), "v"(hi));
  return r;  // D[15:0]=bf16(lo), D[31:16]=bf16(hi)
}

#define LOADF(ptr, j) ((ptr)[(size_t)(j) * CH_STRIDE])

// One wave per (b, h, w-tile of 16). corr[m=w][n=w'] via mfma_f32_16x16x32_bf16:
//   A lane l: x1[m = l&15][k = 8*(l>>4)+j], j=0..7
//   B lane l: x2[k = 8*(l>>4)+j][n = l&15]
//   D lane l, reg q: row m = (l>>4)*4+q, col n = l&15   [m89-verified]
// Band: dj = 16*t + n - m, valid 0..8; w' = w0-4+16t+n.
__global__ __launch_bounds__(256)
void corr_mfma(const float* __restrict__ x1, const float* __restrict__ x2,
               float* __restrict__ out) {
  const int tid  = threadIdx.x;
  const int bid  = blockIdx.x;
  // XCD-chunked swizzle (proven r9): 1536 = 8 XCDs * 192 contiguous
  const int sbid = (bid & 7) * 192 + (bid >> 3);
  const int gwid = sbid * 4 + (tid >> 6);   // 0..6143 = (b*96 + h)*8 + wt
  const int lane = tid & 63;
  const int n16  = lane & 15;
  const int kgrp = lane >> 4;

  const int wt = gwid & 7;
  const int hb = gwid >> 3;
  const int h  = hb % Hh;
  const int b  = hb / Hh;
  const int w0 = wt * 16;

  // A element base: x1[b][kgrp*8 + j][h][w0 + n16]
  const float* pA = x1 + ((size_t)b * Cc * Hh + h) * Ww + (w0 + n16)
                       + (size_t)kgrp * 8 * CH_STRIDE;

  f32x4 acc[9][2];
#pragma unroll
  for (int di = 0; di < 9; ++di) {
#pragma unroll
    for (int t = 0; t < 2; ++t) acc[di][t] = (f32x4){0.f, 0.f, 0.f, 0.f};
  }

  for (int c0 = 0; c0 < Cc; c0 += 32) {
    // ---- A fragment (x1), direct from global + cvt ----
    const float* pAc = pA + (size_t)c0 * CH_STRIDE;
    bf16x8 af;
    {
      union { unsigned u[4]; bf16x8 v; } ux;
      ux.u[0] = cvt_pk(LOADF(pAc, 0), LOADF(pAc, 1));
      ux.u[1] = cvt_pk(LOADF(pAc, 2), LOADF(pAc, 3));
      ux.u[2] = cvt_pk(LOADF(pAc, 4), LOADF(pAc, 5));
      ux.u[3] = cvt_pk(LOADF(pAc, 6), LOADF(pAc, 7));
      af = ux.v;
    }

#pragma unroll
    for (int di = 0; di < 9; ++di) {
      const int h2 = h + di - 4;
      if (h2 >= 0 && h2 < Hh) {            // wave-uniform branch
        const float* pB = x2 + (((size_t)b * Cc + c0) * Hh + h2) * Ww
                             + (size_t)kgrp * 8 * CH_STRIDE;
#pragma unroll
        for (int t = 0; t < 2; ++t) {
          const int wp = w0 - 4 + 16 * t + n16;   // w' for this lane
          float bv[8];
#pragma unroll
          for (int j = 0; j < 8; ++j) bv[j] = 0.f;
          if (wp >= 0 && wp < Ww) {               // per-lane predication
            const float* pBc = pB + wp;
#pragma unroll
            for (int j = 0; j < 8; ++j) bv[j] = LOADF(pBc, j);
          }
          bf16x8 bf_;
          {
            union { unsigned u[4]; bf16x8 v; } ub;
            ub.u[0] = cvt_pk(bv[0], bv[1]);
            ub.u[1] = cvt_pk(bv[2], bv[3]);
            ub.u[2] = cvt_pk(bv[4], bv[5]);
            ub.u[3] = cvt_pk(bv[6], bv[7]);
            bf_ = ub.v;
          }
          acc[di][t] = __builtin_amdgcn_mfma_f32_16x16x32_bf16(
              af, bf_, acc[di][t], 0, 0, 0);
        }
      }
    }
  }

  // ---- epilogue: extract 9-band, scale, predicated scattered stores ----
  const float scale = 1.0f / (float)Cc;
#pragma unroll
  for (int di = 0; di < 9; ++di) {
#pragma unroll
    for (int t = 0; t < 2; ++t) {
#pragma unroll
      for (int q = 0; q < 4; ++q) {
        const int m  = kgrp * 4 + q;         // output w-offset
        const int dj = 16 * t + n16 - m;     // band position
        if (dj >= 0 && dj <= 8) {
          out[(((size_t)b * 81 + di * 9 + dj) * Hh + h) * Ww + (w0 + m)]
              = acc[di][t][q] * scale;
        }
      }
    }
  }
}

extern "C" void kernel_launch(void* const* d_in, const int* in_sizes, int n_in,
                              void* d_out, int out_size, void* d_ws, size_t ws_size,
                              hipStream_t stream) {
  const float* x1 = (const float*)d_in[0];
  const float* x2 = (const float*)d_in[1];
  float* out = (float*)d_out;
  // 8 b * 96 h * 8 wt = 6144 waves = 1536 blocks * 4 waves
  corr_mfma<<<1536, 256, 0, stream>>>(x1, x2, out);
}

// Round 13
// 86.107 us; speedup vs baseline: 11.9732x; 1.4390x over previous
//
#include <hip/hip_runtime.h>

#define Cc 256
#define Hh 96
#define Ww 128
#define CH_STRIDE (Hh * Ww)   // 12288 floats per channel plane
#define TH 4                  // output h-rows per block (4 waves)
#define ROWS (TH + 8)         // 12 staged x2 rows (with +-4 halo)
#define COLS 36               // w0-4 .. w0+31
#define CSL  48               // padded ch slots: 96B col stride (16B-aligned, bank-uniform)

typedef __attribute__((ext_vector_type(8))) short bf16x8;  // 8 bf16 in 4 VGPRs
typedef __attribute__((ext_vector_type(4))) float f32x4;

static __device__ __forceinline__ unsigned cvt_pk(float lo, float hi) {
  unsigned r;
  asm("v_cvt_pk_bf16_f32 %0, %1, %2" : "=v"(r) : "v"(lo), "v"(hi));
  return r;  // D[15:0]=bf16(lo), D[31:16]=bf16(hi)
}

// corr[m=w][n=w'] via mfma_f32_16x16x32_bf16 (layouts as r12, verified PASS):
//   A lane l: x1[m=l&15][k=8*(l>>4)+j];  B lane l: x2[k][n=l&15]
//   D lane l, reg q: row m=(l>>4)*4+q, col n=l&15
__global__ __launch_bounds__(256)
void corr_mfma(const float* __restrict__ x1, const float* __restrict__ x2,
               float* __restrict__ out) {
  __shared__ __align__(16) unsigned short x2s[ROWS * COLS * CSL];  // 41472 B

  const int tid  = threadIdx.x;
  const int bid  = blockIdx.x;
  // XCD-chunked swizzle (proven r9): 1536 = 8 XCDs * 192 contiguous
  const int sbid = (bid & 7) * 192 + (bid >> 3);

  const int wt  = sbid & 7;          // w-tile
  const int hgb = sbid >> 3;         // b*24 + hg
  const int hg  = hgb % 24;
  const int b   = hgb / 24;
  const int h0  = hg * TH;
  const int w0  = wt * 16;

  const int wv   = tid >> 6;         // wave 0..3 -> h = h0+wv
  const int lane = tid & 63;
  const int n16  = lane & 15;
  const int kgrp = lane >> 4;
  const int h    = h0 + wv;

  // A element base: x1[b][kgrp*8 + j][h][w0 + n16]
  const float* pA = x1 + ((size_t)b * Cc * Hh + h) * Ww + (w0 + n16)
                       + (size_t)kgrp * 8 * CH_STRIDE;

  f32x4 acc[9][2];
#pragma unroll
  for (int di = 0; di < 9; ++di)
#pragma unroll
    for (int t = 0; t < 2; ++t) acc[di][t] = (f32x4){0.f, 0.f, 0.f, 0.f};

  for (int c0 = 0; c0 < Cc; c0 += 32) {
    __syncthreads();  // previous chunk's ds_reads done before overwrite

    // ---- stage x2[b][c0..c0+31][h0-4..h0+7][w0-4..w0+31] as bf16 ----
    // unit u = (chg, r, c); consecutive lanes -> consecutive cols (coalesced)
    for (int u = tid; u < 4 * ROWS * COLS; u += 256) {
      const int chg = u / (ROWS * COLS);
      const int rem = u - chg * (ROWS * COLS);
      const int r   = rem / COLS;
      const int c   = rem - r * COLS;
      const int gh  = h0 - 4 + r;
      const int gw  = w0 - 4 + c;
      float v[8];
#pragma unroll
      for (int j = 0; j < 8; ++j) v[j] = 0.f;
      if (gh >= 0 && gh < Hh && gw >= 0 && gw < Ww) {
        const float* q = x2 + ((size_t)(b * Cc + c0 + chg * 8) * Hh + gh) * Ww + gw;
#pragma unroll
        for (int j = 0; j < 8; ++j) v[j] = q[(size_t)j * CH_STRIDE];
      }
      uint4 pk;
      pk.x = cvt_pk(v[0], v[1]);
      pk.y = cvt_pk(v[2], v[3]);
      pk.z = cvt_pk(v[4], v[5]);
      pk.w = cvt_pk(v[6], v[7]);
      *(uint4*)(&x2s[(r * COLS + c) * CSL + chg * 8]) = pk;
    }

    // ---- A fragment (x1), direct from global + cvt ----
    const float* pAc = pA + (size_t)c0 * CH_STRIDE;
    bf16x8 af;
    {
      union { unsigned u[4]; bf16x8 v; } ux;
      ux.u[0] = cvt_pk(pAc[0 * CH_STRIDE], pAc[1 * (size_t)CH_STRIDE]);
      ux.u[1] = cvt_pk(pAc[2 * (size_t)CH_STRIDE], pAc[3 * (size_t)CH_STRIDE]);
      ux.u[2] = cvt_pk(pAc[4 * (size_t)CH_STRIDE], pAc[5 * (size_t)CH_STRIDE]);
      ux.u[3] = cvt_pk(pAc[6 * (size_t)CH_STRIDE], pAc[7 * (size_t)CH_STRIDE]);
      af = ux.v;
    }

    __syncthreads();

    // ---- branch-free compute: 18 ds_read_b128 + 18 MFMA ----
    // B frag (di,t): lane (n16,kgrp) reads x2s[row=wv+di][col=16t+n16][kgrp*8..+7]
#pragma unroll
    for (int di = 0; di < 9; ++di) {
      const int r = wv + di;
#pragma unroll
      for (int t = 0; t < 2; ++t) {
        const bf16x8 bf_ =
            *(const bf16x8*)(&x2s[(r * COLS + 16 * t + n16) * CSL + kgrp * 8]);
        acc[di][t] = __builtin_amdgcn_mfma_f32_16x16x32_bf16(af, bf_, acc[di][t], 0, 0, 0);
      }
    }
  }

  // ---- epilogue: extract 9-band, scale, predicated scattered stores ----
  const float scale = 1.0f / (float)Cc;
#pragma unroll
  for (int di = 0; di < 9; ++di) {
#pragma unroll
    for (int t = 0; t < 2; ++t) {
#pragma unroll
      for (int q = 0; q < 4; ++q) {
        const int m  = kgrp * 4 + q;         // output w-offset in tile
        const int dj = 16 * t + n16 - m;     // band position
        if (dj >= 0 && dj <= 8) {
          out[(((size_t)b * 81 + di * 9 + dj) * Hh + h) * Ww + (w0 + m)]
              = acc[di][t][q] * scale;
        }
      }
    }
  }
}

extern "C" void kernel_launch(void* const* d_in, const int* in_sizes, int n_in,
                              void* d_out, int out_size, void* d_ws, size_t ws_size,
                              hipStream_t stream) {
  const float* x1 = (const float*)d_in[0];
  const float* x2 = (const float*)d_in[1];
  float* out = (float*)d_out;
  // 8 b * 24 hgroups * 8 wt = 1536 blocks * 4 waves
  corr_mfma<<<1536, 256, 0, stream>>>(x1, x2, out);
}

// Round 16
// 66.060 us; speedup vs baseline: 15.6067x; 1.3035x over previous
//
#include <hip/hip_runtime.h>

#define Cc 256
#define Hh 96
#define Ww 128
#define CH_STRIDE (Hh * Ww)   // 12288 floats per channel plane
#define ROWS 16               // TH=8 output rows + 8 halo
#define SCOLS 24              // staged cols: w0-4 .. w0+19 (only band-used cols)
#define ACOLS 32              // addressed cols (t=1 reads reach col 31; 24..31 = garbage,
                              //  lands only in dj>8 outputs which are discarded)
#define CSL  48               // shorts per (row,col) cell: 96B stride, 16B-aligned
#define UNITS 3               // staging units/thread: 4*16*24 / 512

typedef __attribute__((ext_vector_type(8))) short bf16x8;  // 8 bf16 in 4 VGPRs
typedef __attribute__((ext_vector_type(4))) float f32x4;

static __device__ __forceinline__ unsigned cvt_pk(float lo, float hi) {
  unsigned r;
  asm("v_cvt_pk_bf16_f32 %0, %1, %2" : "=v"(r) : "v"(lo), "v"(hi));
  return r;  // D[15:0]=bf16(lo), D[31:16]=bf16(hi)
}

// corr[m=w][n=w'] via mfma_f32_16x16x32_bf16 (layouts verified PASS r12/r13):
//   A lane l: x1[m=l&15][k=8*(l>>4)+j];  B lane l: x2[k][n=l&15]
//   D lane l, reg q: row m=(l>>4)*4+q, col n=l&15
__global__ __launch_bounds__(512)
void corr_mfma(const float* __restrict__ x1, const float* __restrict__ x2,
               float* __restrict__ out) {
  __shared__ __align__(16) unsigned short x2s[ROWS * ACOLS * CSL];  // 49152 B

  const int tid  = threadIdx.x;
  const int bid  = blockIdx.x;
  // XCD-chunked swizzle (proven r9): 768 = 8 XCDs * 96 contiguous
  const int sbid = (bid & 7) * 96 + (bid >> 3);

  const int wt  = sbid & 7;          // w-tile
  const int hgb = sbid >> 3;         // b*12 + hg
  const int hg  = hgb % 12;
  const int b   = hgb / 12;
  const int h0  = hg * 8;
  const int w0  = wt * 16;

  const int wv   = tid >> 6;         // wave 0..7 -> h = h0+wv
  const int lane = tid & 63;
  const int n16  = lane & 15;
  const int kgrp = lane >> 4;
  const int h    = h0 + wv;

  // ---- staging unit geometry (3 uniform units/thread, all static) ----
  const float* uptr[UNITS];
  int  uoff[UNITS];
  bool uok[UNITS];
#pragma unroll
  for (int s = 0; s < UNITS; ++s) {
    const int u   = tid + 512 * s;       // 0..1535
    const int chg = u / 384;             // channel group 0..3 (8 ch each)
    const int rem = u - chg * 384;
    const int r   = rem / SCOLS;         // staged row 0..15
    const int c   = rem - r * SCOLS;     // staged col 0..23
    const int gh  = h0 - 4 + r;
    const int gw  = w0 - 4 + c;
    uok[s] = (gh >= 0) & (gh < Hh) & (gw >= 0) & (gw < Ww);
    const int ghc = uok[s] ? gh : 0;     // clamp addr; value zeroed below
    const int gwc = uok[s] ? gw : 0;
    uptr[s] = x2 + ((size_t)(b * Cc + chg * 8) * Hh + ghc) * Ww + gwc;
    uoff[s] = (r * ACOLS + c) * CSL + chg * 8;
  }

  // A element base: x1[b][kgrp*8 + j][h][w0 + n16]
  const float* pA = x1 + ((size_t)b * Cc * Hh + h) * Ww + (w0 + n16)
                       + (size_t)kgrp * 8 * CH_STRIDE;

  f32x4 acc[9][2];
#pragma unroll
  for (int di = 0; di < 9; ++di)
#pragma unroll
    for (int t = 0; t < 2; ++t) acc[di][t] = (f32x4){0.f, 0.f, 0.f, 0.f};

  // ---- T14 prologue: prefetch chunk 0 into registers ----
  float pf[UNITS][8];
#pragma unroll
  for (int s = 0; s < UNITS; ++s)
#pragma unroll
    for (int j = 0; j < 8; ++j)
      pf[s][j] = uok[s] ? uptr[s][(size_t)j * CH_STRIDE] : 0.f;

  for (int ci = 0; ci < 8; ++ci) {
    const int c0 = ci * 32;
    __syncthreads();  // previous chunk's ds_reads done before overwrite

    // A loads for current chunk: issue early, consumed after LDS write
    float pa[8];
    {
      const float* pAc = pA + (size_t)c0 * CH_STRIDE;
#pragma unroll
      for (int j = 0; j < 8; ++j) pa[j] = pAc[(size_t)j * CH_STRIDE];
    }

    // LDS write from prefetched regs (latency already hidden under prev compute)
#pragma unroll
    for (int s = 0; s < UNITS; ++s) {
      uint4 pk;
      pk.x = cvt_pk(pf[s][0], pf[s][1]);
      pk.y = cvt_pk(pf[s][2], pf[s][3]);
      pk.z = cvt_pk(pf[s][4], pf[s][5]);
      pk.w = cvt_pk(pf[s][6], pf[s][7]);
      *(uint4*)(&x2s[uoff[s]]) = pk;
    }

    // A fragment
    bf16x8 af;
    {
      union { unsigned u[4]; bf16x8 v; } ux;
      ux.u[0] = cvt_pk(pa[0], pa[1]);
      ux.u[1] = cvt_pk(pa[2], pa[3]);
      ux.u[2] = cvt_pk(pa[4], pa[5]);
      ux.u[3] = cvt_pk(pa[6], pa[7]);
      af = ux.v;
    }

    // prefetch NEXT chunk (in flight across barrier + compute)
    if (ci < 7) {
      const size_t nb = (size_t)(c0 + 32) * CH_STRIDE;
#pragma unroll
      for (int s = 0; s < UNITS; ++s)
#pragma unroll
        for (int j = 0; j < 8; ++j)
          pf[s][j] = uok[s] ? uptr[s][nb + (size_t)j * CH_STRIDE] : 0.f;
    }

    __syncthreads();  // LDS ready

    // branch-free compute: 18 ds_read_b128 + 18 MFMA per wave
#pragma unroll
    for (int di = 0; di < 9; ++di) {
      const int r = wv + di;
#pragma unroll
      for (int t = 0; t < 2; ++t) {
        const bf16x8 bf_ =
            *(const bf16x8*)(&x2s[(r * ACOLS + 16 * t + n16) * CSL + kgrp * 8]);
        acc[di][t] = __builtin_amdgcn_mfma_f32_16x16x32_bf16(af, bf_, acc[di][t], 0, 0, 0);
      }
    }
  }

  // ---- epilogue: extract 9-band, scale, predicated scattered stores ----
  const float scale = 1.0f / (float)Cc;
#pragma unroll
  for (int di = 0; di < 9; ++di) {
#pragma unroll
    for (int t = 0; t < 2; ++t) {
#pragma unroll
      for (int q = 0; q < 4; ++q) {
        const int m  = kgrp * 4 + q;         // output w-offset in tile
        const int dj = 16 * t + n16 - m;     // band position
        if (dj >= 0 && dj <= 8) {
          out[(((size_t)b * 81 + di * 9 + dj) * Hh + h) * Ww + (w0 + m)]
              = acc[di][t][q] * scale;
        }
      }
    }
  }
}

extern "C" void kernel_launch(void* const* d_in, const int* in_sizes, int n_in,
                              void* d_out, int out_size, void* d_ws, size_t ws_size,
                              hipStream_t stream) {
  const float* x1 = (const float*)d_in[0];
  const float* x2 = (const float*)d_in[1];
  float* out = (float*)d_out;
  // 8 b * 12 hgroups * 8 wt = 768 blocks * 8 waves
  corr_mfma<<<768, 512, 0, stream>>>(x1, x2, out);
}